// Round 13
// baseline (575.843 us; speedup 1.0000x reference)
//
#include <hip/hip_runtime.h>

#define NNODE 6144
#define FEATD 512
#define HIDD  512
#define NCLSD 64
#define NMSK  (NNODE/64)   // 96 mask words per row
#define LALPHA 0.2f

typedef unsigned short ushort_t;
typedef unsigned long long u64_t;
typedef short bf16x8 __attribute__((ext_vector_type(8)));
typedef float f32x4 __attribute__((ext_vector_type(4)));

__device__ __forceinline__ float lrelu(float x){ return x > 0.f ? x : LALPHA * x; }

__device__ __forceinline__ ushort_t f2b(float x){
    union { float f; unsigned u; } v; v.f = x;
    unsigned r = v.u + 0x7fffu + ((v.u >> 16) & 1u);
    return (ushort_t)(r >> 16);
}
__device__ __forceinline__ float b2f(ushort_t u){
    union { unsigned u; float f; } v; v.u = ((unsigned)u) << 16; return v.f;
}

// Runtime C/D-layout calibration (round-8 validated)
__device__ __forceinline__ void calib_cd(int lm, int* qrow, int* vcol){
    bf16x8 ai, as;
    ushort_t vi = f2b((float)(lm + 1));
    ushort_t vs = f2b(0.03125f);
    #pragma unroll
    for (int e = 0; e < 8; e++){ ((ushort_t*)&ai)[e] = vi; ((ushort_t*)&as)[e] = vs; }
    f32x4 z = {0.f, 0.f, 0.f, 0.f};
    f32x4 d1 = __builtin_amdgcn_mfma_f32_16x16x32_bf16(ai, as, z, 0, 0, 0);
    f32x4 d2 = __builtin_amdgcn_mfma_f32_16x16x32_bf16(as, ai, z, 0, 0, 0);
    #pragma unroll
    for (int r = 0; r < 4; r++){
        qrow[r] = (int)(d1[r] + 0.5f) - 1;
        vcol[r] = (int)(d2[r] + 0.5f) - 1;
    }
}

// ---------------- adj (int32) -> bitmask ----------------
__global__ void k_adjmask(const int* __restrict__ adj, u64_t* __restrict__ mask){
    int lane = threadIdx.x & 63;
    size_t wid = ((size_t)blockIdx.x * blockDim.x + threadIdx.x) >> 6;
    size_t nw = (size_t)NNODE * NNODE / 64;
    size_t stride = ((size_t)gridDim.x * blockDim.x) >> 6;
    for (size_t q = wid; q < nw; q += stride){
        int a = adj[q * 64 + lane];
        u64_t b = __ballot(a > 0);
        if (lane == 0) mask[q] = b;
    }
}

// out1[r]=W[r]·a[0:K]; out2[r]=W[r]·a[K:2K]  (one wave per row)
__global__ void k_fold(const float* __restrict__ W, const float* __restrict__ a,
                       float* __restrict__ out1, float* __restrict__ out2, int K){
    int row  = (blockIdx.x * blockDim.x + threadIdx.x) >> 6;
    int lane = threadIdx.x & 63;
    const float* wr = W + (size_t)row * K;
    float s1 = 0.f, s2 = 0.f;
    for (int c = lane; c < K; c += 64){ float w = wr[c]; s1 += w * a[c]; s2 += w * a[K + c]; }
    #pragma unroll
    for (int m = 32; m; m >>= 1){ s1 += __shfl_xor(s1, m); s2 += __shfl_xor(s2, m); }
    if (lane == 0){ out1[row] = s1; out2[row] = s2; }
}

// ---------------- o1/o2 = A @ {v1,v2}  (one wave per row) ----------------
__global__ void k_rowvec2_f32(const float* __restrict__ A, const float* __restrict__ v1,
                              const float* __restrict__ v2, float* __restrict__ o1,
                              float* __restrict__ o2, int K){
    int row  = (blockIdx.x * blockDim.x + threadIdx.x) >> 6;
    int lane = threadIdx.x & 63;
    const float* r = A + (size_t)row * K;
    float s1 = 0.f, s2 = 0.f;
    for (int c = lane; c < K; c += 64){ float x = r[c]; s1 += x * v1[c]; s2 += x * v2[c]; }
    #pragma unroll
    for (int m = 32; m; m >>= 1){ s1 += __shfl_xor(s1, m); s2 += __shfl_xor(s2, m); }
    if (lane == 0){ o1[row] = s1; o2[row] = s2; }
}

// ---------------- dst[c*R + r] = bf16(src[r*C + c]) ----------------
__global__ void k_transpose_bf16(const float* __restrict__ src, ushort_t* __restrict__ dst,
                                 int R, int C){
    int idx = blockIdx.x * blockDim.x + threadIdx.x;
    if (idx >= R * C) return;
    int r = idx / C, c = idx - r * C;
    dst[(size_t)c * R + r] = f2b(src[idx]);
}

// ---------------- *out = max(x[0..n)) ----------------
__global__ void k_max(const float* __restrict__ x, int n, float* __restrict__ out){
    __shared__ float sm[16];
    float m = -3.0e38f;
    for (int i = threadIdx.x; i < n; i += blockDim.x) m = fmaxf(m, x[i]);
    #pragma unroll
    for (int s = 32; s; s >>= 1) m = fmaxf(m, __shfl_xor(m, s));
    if ((threadIdx.x & 63) == 0) sm[threadIdx.x >> 6] = m;
    __syncthreads();
    if (threadIdx.x == 0){
        float mm = sm[0];
        for (int i = 1; i < (int)(blockDim.x >> 6); i++) mm = fmaxf(mm, sm[i]);
        *out = mm;
    }
}

// ---------------- zero fp32 buffer (float4) ----------------
__global__ void k_zero(float* __restrict__ p, int n4){
    int i = blockIdx.x * blockDim.x + threadIdx.x;
    if (i < n4) ((float4*)p)[i] = make_float4(0.f, 0.f, 0.f, 0.f);
}

// ---------------- Wh1^T = (X @ Wg)^T  via MFMA, single bf16 ----------------
__global__ __launch_bounds__(512) void k_gemm_xw(const float* __restrict__ X,
        const ushort_t* __restrict__ B, ushort_t* __restrict__ WhT){
    int i0 = blockIdx.x * 16;
    int w = threadIdx.x >> 6, l = threadIdx.x & 63, lm = l & 15, lh = l >> 4;
    int c0 = w * 64;
    int qrow[4], vcol[4];
    calib_cd(lm, qrow, vcol);
    f32x4 acc[4] = {};
    const float* xp = X + (size_t)(i0 + lm) * FEATD + lh * 8;
    for (int k0 = 0; k0 < FEATD; k0 += 32){
        float4 x0 = *(const float4*)(xp + k0);
        float4 x1 = *(const float4*)(xp + k0 + 4);
        float xa[8] = {x0.x, x0.y, x0.z, x0.w, x1.x, x1.y, x1.z, x1.w};
        bf16x8 af;
        #pragma unroll
        for (int e = 0; e < 8; e++) ((ushort_t*)&af)[e] = f2b(xa[e]);
        #pragma unroll
        for (int t = 0; t < 4; t++){
            bf16x8 bf = *(const bf16x8*)(B + (size_t)(c0 + t*16 + lm) * FEATD + k0 + lh * 8);
            acc[t] = __builtin_amdgcn_mfma_f32_16x16x32_bf16(af, bf, acc[t], 0, 0, 0);
        }
    }
    #pragma unroll
    for (int t = 0; t < 4; t++)
        #pragma unroll
        for (int r = 0; r < 4; r++)
            WhT[(size_t)(c0 + t*16 + vcol[r]) * NNODE + i0 + qrow[r]] = f2b(acc[t][r]);
}

// ---------------- Wh2 = res @ Wo via MFMA; emits fp32 Wh2 + bf16 Wh2^T ----------------
__global__ __launch_bounds__(256) void k_gemm_out(const float* __restrict__ res,
        const ushort_t* __restrict__ BT, float* __restrict__ Wh2, ushort_t* __restrict__ Wh2T){
    int w = threadIdx.x >> 6, l = threadIdx.x & 63, lm = l & 15, lh = l >> 4;
    int i0 = blockIdx.x * 64 + w * 16;
    int qrow[4], vcol[4];
    calib_cd(lm, qrow, vcol);
    f32x4 acc[4] = {};
    const float* ap = res + (size_t)(i0 + lm) * HIDD + lh * 8;
    for (int k0 = 0; k0 < HIDD; k0 += 32){
        float4 x0 = *(const float4*)(ap + k0);
        float4 x1 = *(const float4*)(ap + k0 + 4);
        float xa[8] = {x0.x, x0.y, x0.z, x0.w, x1.x, x1.y, x1.z, x1.w};
        bf16x8 af;
        #pragma unroll
        for (int e = 0; e < 8; e++) ((ushort_t*)&af)[e] = f2b(xa[e]);
        #pragma unroll
        for (int t = 0; t < 4; t++){
            bf16x8 bf = *(const bf16x8*)(BT + (size_t)(t*16 + lm) * HIDD + k0 + lh * 8);
            acc[t] = __builtin_amdgcn_mfma_f32_16x16x32_bf16(af, bf, acc[t], 0, 0, 0);
        }
    }
    #pragma unroll
    for (int t = 0; t < 4; t++){
        #pragma unroll
        for (int r = 0; r < 4; r++){
            int row = i0 + qrow[r], col = t*16 + vcol[r];
            float v = acc[t][r];
            Wh2[(size_t)row * NCLSD + col] = v;
            Wh2T[(size_t)col * NNODE + row] = f2b(v);
        }
    }
}

// ---------------- P-gen: materialize P (bf16) + exact fp32 row sums ----------------
__global__ __launch_bounds__(256) void k_pgen(const u64_t* __restrict__ mask,
        const float* __restrict__ e1, const float* __restrict__ e2,
        const float* __restrict__ e2max, ushort_t* __restrict__ P, float* __restrict__ lsum){
    __shared__ float e2s[NNODE];
    __shared__ u64_t msk[16][NMSK + 1];
    int i0 = blockIdx.x * 16;
    int tid = threadIdx.x;
    int r = tid >> 4, q = tid & 15;
    for (int k = tid; k < NNODE; k += 256) e2s[k] = e2[k];
    for (int k = tid; k < 16 * NMSK; k += 256) msk[k / NMSK][k % NMSK] = mask[(size_t)i0 * NMSK + k];
    __syncthreads();
    float e1i = e1[i0 + r];
    float M = lrelu(e1i + *e2max);   // exact upper bound (softmax shift-invariant)
    float rsum = 0.f;
    ushort_t* prow = P + (size_t)(i0 + r) * NNODE;
    for (int j0 = 0; j0 < NNODE; j0 += 128){
        int j = j0 + q * 8;
        u64_t word = msk[r][j >> 6];
        int sh = j & 63;
        float4 fA = *(const float4*)&e2s[j];
        float4 fB = *(const float4*)&e2s[j + 4];
        float ea[8] = {fA.x, fA.y, fA.z, fA.w, fB.x, fB.y, fB.z, fB.w};
        bf16x8 pk;
        #pragma unroll
        for (int e = 0; e < 8; e++){
            float p = ((word >> (sh + e)) & 1ull) ? __expf(lrelu(e1i + ea[e]) - M) : 0.f;
            ushort_t pb = f2b(p);
            ((ushort_t*)&pk)[e] = pb;
            rsum += b2f(pb);
        }
        *(bf16x8*)(prow + j) = pk;
    }
    #pragma unroll
    for (int o = 8; o; o >>= 1) rsum += __shfl_xor(rsum, o);
    if (q == 0) lsum[i0 + r] = rsum;
}

// ---------------- GAT1 GEMM v2: K-split x2, atomic fp32 accumulate ----------------
// grid 1536: bid = [a(96)][kc(2)][b8(8)]; b8 -> (ch, rg&3) keeps XCD<->col-half affinity.
// Each block: 16 rows x 256 cols over K-chunk of 3072; 4 waves of 16x64.
#define KCH 3072
__global__ __launch_bounds__(256) void k_gat1g(const ushort_t* __restrict__ P,
        const ushort_t* __restrict__ V, float* __restrict__ resf){
    int bid = blockIdx.x;
    int b8 = bid & 7;
    int kc = (bid >> 3) & 1;
    int a  = bid >> 4;
    int ch = b8 >> 2;
    int rg = a * 4 + (b8 & 3);
    int i0 = rg * 16;
    int kb = kc * KCH;
    int tid = threadIdx.x;
    int w = tid >> 6, l = tid & 63, lm = l & 15, lh = l >> 4;
    int cbase = ch * 256 + w * 64;
    int qrow[4], vcol[4];
    calib_cd(lm, qrow, vcol);
    f32x4 acc[4] = {};
    const ushort_t* Ap = P + (size_t)(i0 + lm) * NNODE + kb + lh * 8;
    const ushort_t* vb[4];
    #pragma unroll
    for (int t = 0; t < 4; t++) vb[t] = V + (size_t)(cbase + t*16 + lm) * NNODE + kb + lh * 8;
    bf16x8 a0c = *(const bf16x8*)(Ap);
    bf16x8 a1c = *(const bf16x8*)(Ap + 32);
    bf16x8 vc[4][2], vn[4][2], a0n = {}, a1n = {};
    #pragma unroll
    for (int t = 0; t < 4; t++){
        vc[t][0] = *(const bf16x8*)(vb[t]);
        vc[t][1] = *(const bf16x8*)(vb[t] + 32);
    }
    for (int j0 = 0; j0 < KCH; j0 += 64){
        int jn = j0 + 64;
        if (jn < KCH){
            a0n = *(const bf16x8*)(Ap + jn);
            a1n = *(const bf16x8*)(Ap + jn + 32);
            #pragma unroll
            for (int t = 0; t < 4; t++){
                vn[t][0] = *(const bf16x8*)(vb[t] + jn);
                vn[t][1] = *(const bf16x8*)(vb[t] + jn + 32);
            }
        }
        #pragma unroll
        for (int t = 0; t < 4; t++){
            acc[t] = __builtin_amdgcn_mfma_f32_16x16x32_bf16(a0c, vc[t][0], acc[t], 0, 0, 0);
            acc[t] = __builtin_amdgcn_mfma_f32_16x16x32_bf16(a1c, vc[t][1], acc[t], 0, 0, 0);
        }
        a0c = a0n; a1c = a1n;
        #pragma unroll
        for (int t = 0; t < 4; t++){ vc[t][0] = vn[t][0]; vc[t][1] = vn[t][1]; }
    }
    #pragma unroll
    for (int t = 0; t < 4; t++)
        #pragma unroll
        for (int r = 0; r < 4; r++)
            atomicAdd(&resf[(size_t)(i0 + qrow[r]) * HIDD + cbase + t*16 + vcol[r]], acc[t][r]);
}

// ---------------- finish: res = elu(res / lsum[row]) ----------------
__global__ void k_fin(float* __restrict__ res, const float* __restrict__ lsum){
    int i = blockIdx.x * blockDim.x + threadIdx.x;   // float4 index
    int row = i >> 7;                                 // 128 float4 per row (512 cols)
    float den = lsum[row];
    float4 v = ((float4*)res)[i];
    float* vp = (float*)&v;
    #pragma unroll
    for (int k = 0; k < 4; k++){
        float x = vp[k] / den;
        vp[k] = x > 0.f ? x : expm1f(x);
    }
    ((float4*)res)[i] = v;
}

// ---------------- GAT layer 1 fallback (register P) + swizzle ----------------
__global__ __launch_bounds__(256) void k_gat1(const u64_t* __restrict__ mask,
        const float* __restrict__ e1, const float* __restrict__ e2,
        const float* __restrict__ e2max,
        const ushort_t* __restrict__ V, float* __restrict__ res){
    __shared__ __align__(16) float e2s[NNODE];
    __shared__ u64_t msk[16][NMSK + 1];
    int bid = blockIdx.x;
    int b8 = bid & 7, a = bid >> 3;
    int ch = b8 >> 2;
    int rg = a * 4 + (b8 & 3);
    int i0 = rg * 16;
    int tid = threadIdx.x;
    int w = tid >> 6, l = tid & 63, lm = l & 15, lh = l >> 4;
    int cbase = ch * 256 + w * 64;
    int qrow[4], vcol[4];
    calib_cd(lm, qrow, vcol);
    for (int k = tid; k < NNODE; k += 256) e2s[k] = e2[k];
    for (int k = tid; k < 16 * NMSK; k += 256) msk[k / NMSK][k % NMSK] = mask[(size_t)i0 * NMSK + k];
    __syncthreads();
    float e1i = e1[i0 + lm];
    float M = lrelu(e1i + *e2max);
    float lsum = 0.f;
    f32x4 acc[4] = {};
    const ushort_t* vb[4];
    #pragma unroll
    for (int t = 0; t < 4; t++) vb[t] = V + (size_t)(cbase + t*16 + lm) * NNODE + lh * 8;
    bf16x8 vc[4][2], vn[4][2];
    #pragma unroll
    for (int t = 0; t < 4; t++)
        #pragma unroll
        for (int h = 0; h < 2; h++) vc[t][h] = *(const bf16x8*)(vb[t] + h*32);
    for (int j0 = 0; j0 < NNODE; j0 += 64){
        u64_t word = msk[lm][j0 >> 6];
        int jn = j0 + 64;
        if (jn < NNODE){
            #pragma unroll
            for (int t = 0; t < 4; t++)
                #pragma unroll
                for (int h = 0; h < 2; h++) vn[t][h] = *(const bf16x8*)(vb[t] + jn + h*32);
        }
        #pragma unroll
        for (int h = 0; h < 2; h++){
            int jb = j0 + h*32 + lh*8;
            float4 fA = *(const float4*)&e2s[jb];
            float4 fB = *(const float4*)&e2s[jb + 4];
            float ea[8] = {fA.x, fA.y, fA.z, fA.w, fB.x, fB.y, fB.z, fB.w};
            int sh = h*32 + lh*8;
            bf16x8 pk;
            float ls = 0.f;
            #pragma unroll
            for (int e = 0; e < 8; e++){
                float p = ((word >> (sh + e)) & 1ull) ? __expf(lrelu(e1i + ea[e]) - M) : 0.f;
                ushort_t pb = f2b(p);
                ((ushort_t*)&pk)[e] = pb;
                ls += b2f(pb);
            }
            lsum += ls;
            #pragma unroll
            for (int t = 0; t < 4; t++)
                acc[t] = __builtin_amdgcn_mfma_f32_16x16x32_bf16(pk, vc[t][h], acc[t], 0, 0, 0);
        }
        #pragma unroll
        for (int t = 0; t < 4; t++)
            #pragma unroll
            for (int h = 0; h < 2; h++) vc[t][h] = vn[t][h];
    }
    lsum += __shfl_xor(lsum, 16);
    lsum += __shfl_xor(lsum, 32);
    #pragma unroll
    for (int t = 0; t < 4; t++){
        #pragma unroll
        for (int r = 0; r < 4; r++){
            float den = __shfl(lsum, qrow[r]);
            int row = qrow[r];
            int col = cbase + t*16 + vcol[r];
            float v = acc[t][r] / den;
            v = v > 0.f ? v : expm1f(v);
            res[(size_t)(i0 + row) * HIDD + col] = v;
        }
    }
}

// ---------------- GAT layer 2: 8-wave j-split, barrier-free loop ----------------
#define JSPAN (NNODE/8)
__global__ __launch_bounds__(512) void k_gat2(const u64_t* __restrict__ mask,
        const float* __restrict__ o1, const float* __restrict__ o2,
        const float* __restrict__ t1, const float* __restrict__ t2,
        const float* __restrict__ o2max, const float* __restrict__ t2max,
        const ushort_t* __restrict__ V2, float* __restrict__ out2){
    __shared__ float accs[8][16][64];
    __shared__ float lsums[8][16];
    __shared__ u64_t msk[16][NMSK + 1];
    int i0 = blockIdx.x * 16;
    int tid = threadIdx.x;
    int w = tid >> 6, l = tid & 63, lm = l & 15, lh = l >> 4;
    for (int k = tid; k < 16 * NMSK; k += 512) msk[k / NMSK][k % NMSK] = mask[(size_t)i0 * NMSK + k];
    __syncthreads();
    int qrow[4], vcol[4];
    calib_cd(lm, qrow, vcol);
    int jbase = w * JSPAN;
    float o1v = o1[i0 + lm], t1v = t1[i0 + lm];
    float M = lrelu(o1v + *o2max) + lrelu(t1v + *t2max);
    float lsum = 0.f;
    f32x4 acc[4] = {};
    const float* o2p = o2 + jbase + lh * 8;
    const float* t2p = t2 + jbase + lh * 8;
    float4 oA = *(const float4*)(o2p), oB = *(const float4*)(o2p + 4);
    float4 tA = *(const float4*)(t2p), tB = *(const float4*)(t2p + 4);
    bf16x8 vcur[4], vnxt[4];
    #pragma unroll
    for (int t = 0; t < 4; t++)
        vcur[t] = *(const bf16x8*)(V2 + (size_t)(t*16 + lm) * NNODE + jbase + lh * 8);

    for (int js = 0; js < JSPAN; js += 32){
        u64_t w64 = msk[lm][(jbase + js) >> 6];
        int sh = (js + lh * 8) & 63;
        float oa[8] = {oA.x, oA.y, oA.z, oA.w, oB.x, oB.y, oB.z, oB.w};
        float ta[8] = {tA.x, tA.y, tA.z, tA.w, tB.x, tB.y, tB.z, tB.w};
        bf16x8 pk;
        float ls = 0.f;
        #pragma unroll
        for (int e = 0; e < 8; e++){
            float p = ((w64 >> (sh + e)) & 1ull) ?
                      __expf(lrelu(o1v + oa[e]) + lrelu(t1v + ta[e]) - M) : 0.f;
            ushort_t pb = f2b(p);
            ((ushort_t*)&pk)[e] = pb;
            ls += b2f(pb);
        }
        lsum += ls;
        int jn = js + 32;
        if (jn < JSPAN){
            oA = *(const float4*)(o2p + jn); oB = *(const float4*)(o2p + jn + 4);
            tA = *(const float4*)(t2p + jn); tB = *(const float4*)(t2p + jn + 4);
            #pragma unroll
            for (int t = 0; t < 4; t++)
                vnxt[t] = *(const bf16x8*)(V2 + (size_t)(t*16 + lm) * NNODE + jbase + jn + lh * 8);
        }
        #pragma unroll
        for (int t = 0; t < 4; t++)
            acc[t] = __builtin_amdgcn_mfma_f32_16x16x32_bf16(pk, vcur[t], acc[t], 0, 0, 0);
        #pragma unroll
        for (int t = 0; t < 4; t++) vcur[t] = vnxt[t];
    }
    lsum += __shfl_xor(lsum, 16);
    lsum += __shfl_xor(lsum, 32);
    if (lh == 0) lsums[w][lm] = lsum;
    #pragma unroll
    for (int t = 0; t < 4; t++)
        #pragma unroll
        for (int r = 0; r < 4; r++)
            accs[w][qrow[r]][t*16 + vcol[r]] = acc[t][r];
    __syncthreads();
    #pragma unroll
    for (int rr = 0; rr < 2; rr++){
        int row = w * 2 + rr;
        float den = 0.f, v = 0.f;
        #pragma unroll
        for (int q = 0; q < 8; q++){ den += lsums[q][row]; v += accs[q][row][l]; }
        out2[(size_t)(i0 + row) * NCLSD + l] = v / den;
    }
}

// ---------------- row-wise log_softmax over 64 classes ----------------
__global__ void k_logsoftmax(const float* __restrict__ out2, float* __restrict__ out){
    int w = threadIdx.x >> 6, l = threadIdx.x & 63;
    int row = blockIdx.x * 4 + w;
    float v = out2[(size_t)row * NCLSD + l];
    float mx = v;
    #pragma unroll
    for (int o = 32; o; o >>= 1) mx = fmaxf(mx, __shfl_xor(mx, o));
    float ex = __expf(v - mx);
    #pragma unroll
    for (int o = 32; o; o >>= 1) ex += __shfl_xor(ex, o);
    out[(size_t)row * NCLSD + l] = v - mx - logf(ex);
}

// ---------------- launch ----------------
extern "C" void kernel_launch(void* const* d_in, const int* in_sizes, int n_in,
                              void* d_out, int out_size, void* d_ws, size_t ws_size,
                              hipStream_t stream){
    const float* X   = (const float*)d_in[0];
    const int*   adj = (const int*)d_in[1];
    const float* Wg  = (const float*)d_in[2];
    const float* ag  = (const float*)d_in[3];
    const float* Wt  = (const float*)d_in[4];
    const float* at  = (const float*)d_in[5];
    const float* Wo  = (const float*)d_in[6];
    const float* ao  = (const float*)d_in[7];
    float* out = (float*)d_out;

    char* ws = (char*)d_ws;
    size_t off = 0;
    auto take = [&](size_t n){ char* p = ws + off; off = (off + n + 255) & ~(size_t)255; return p; };
    u64_t*    maskb = (u64_t*)take((size_t)NNODE * NMSK * 8);
    ushort_t* WhT   = (ushort_t*)take((size_t)HIDD * NNODE * 2);
    float*    res   = (float*)take((size_t)NNODE * HIDD * 4);
    float*    Wh2   = (float*)take((size_t)NNODE * NCLSD * 4);
    ushort_t* Wh2T  = (ushort_t*)take((size_t)NCLSD * NNODE * 2);
    ushort_t* WgT   = (ushort_t*)take((size_t)FEATD * HIDD * 2);
    ushort_t* WoT   = (ushort_t*)take((size_t)HIDD * NCLSD * 2);
    float* e1v  = (float*)take(NNODE * 4);
    float* e2v  = (float*)take(NNODE * 4);
    float* t1v  = (float*)take(NNODE * 4);
    float* t2v  = (float*)take(NNODE * 4);
    float* o1v  = (float*)take(NNODE * 4);
    float* o2v  = (float*)take(NNODE * 4);
    float* wg1  = (float*)take(FEATD * 4);
    float* wg2  = (float*)take(FEATD * 4);
    float* wt1  = (float*)take(HIDD * 4);
    float* wt2  = (float*)take(HIDD * 4);
    float* scal = (float*)take(256);
    float* e2m = scal, * t2m = scal + 1, * o2m = scal + 2;
    float* out2 = Wh2;   // alias: gat2 reads only Wh2T/vectors

    // P materialization buffer (allocated last; only used if ws is big enough)
    size_t pbytes = (size_t)NNODE * NNODE * 2;
    bool bigws = (off + pbytes + NNODE * 4 + 4096) <= ws_size;
    ushort_t* Pbuf  = bigws ? (ushort_t*)take(pbytes) : nullptr;
    float*    lsumv = bigws ? (float*)take(NNODE * 4) : nullptr;

    // adj -> bitmask (reads adj once)
    k_adjmask<<<dim3(2048), dim3(256), 0, stream>>>(adj, maskb);
    // weight prep
    k_transpose_bf16<<<dim3((FEATD*HIDD + 255)/256), dim3(256), 0, stream>>>(Wg, WgT, FEATD, HIDD);
    k_transpose_bf16<<<dim3((HIDD*NCLSD + 255)/256), dim3(256), 0, stream>>>(Wo, WoT, HIDD, NCLSD);
    k_fold<<<dim3(FEATD/4), dim3(256), 0, stream>>>(Wg, ag, wg1, wg2, HIDD);
    k_fold<<<dim3(HIDD/4),  dim3(256), 0, stream>>>(Wt, at, wt1, wt2, HIDD);
    // layer-1 scores (exact fp32 fold)
    k_rowvec2_f32<<<dim3(NNODE/4), dim3(256), 0, stream>>>(X, wg1, wg2, e1v, e2v, FEATD);
    k_max<<<dim3(1), dim3(1024), 0, stream>>>(e2v, NNODE, e2m);
    // Wh1^T via MFMA
    k_gemm_xw<<<dim3(NNODE/16), dim3(512), 0, stream>>>(X, WgT, WhT);
    // GAT layer 1
    if (bigws){
        k_pgen<<<dim3(NNODE/16), dim3(256), 0, stream>>>(maskb, e1v, e2v, e2m, Pbuf, lsumv);
        k_zero<<<dim3((NNODE*HIDD/4 + 255)/256), dim3(256), 0, stream>>>(res, NNODE*HIDD/4);
        k_gat1g<<<dim3(NNODE/16 * 2 * 2), dim3(256), 0, stream>>>(Pbuf, WhT, res);
        k_fin<<<dim3((NNODE*HIDD/4 + 255)/256), dim3(256), 0, stream>>>(res, lsumv);
    } else {
        k_gat1<<<dim3(NNODE/16 * 2), dim3(256), 0, stream>>>(maskb, e1v, e2v, e2m, WhT, res);
    }
    // tree scores via fold
    k_rowvec2_f32<<<dim3(NNODE/4), dim3(256), 0, stream>>>(res, wt1, wt2, t1v, t2v, HIDD);
    k_max<<<dim3(1), dim3(1024), 0, stream>>>(t2v, NNODE, t2m);
    // layer-2 prep (MFMA; emits Wh2 fp32 + Wh2T bf16)
    k_gemm_out<<<dim3(NNODE/64), dim3(256), 0, stream>>>(res, WoT, Wh2, Wh2T);
    k_rowvec2_f32<<<dim3(NNODE/4), dim3(256), 0, stream>>>(Wh2, ao, ao + NCLSD, o1v, o2v, NCLSD);
    k_max<<<dim3(1), dim3(1024), 0, stream>>>(o2v, NNODE, o2m);
    // GAT layer 2 + log_softmax
    k_gat2<<<dim3(NNODE/16), dim3(512), 0, stream>>>(maskb, o1v, o2v, t1v, t2v, o2m, t2m, Wh2T, out2);
    k_logsoftmax<<<dim3(NNODE/4), dim3(256), 0, stream>>>(out2, out);
}

// Round 14
// 336.922 us; speedup vs baseline: 1.7091x; 1.7091x over previous
//
#include <hip/hip_runtime.h>

#define NNODE 6144
#define FEATD 512
#define HIDD  512
#define NCLSD 64
#define NMSK  (NNODE/64)   // 96 mask words per row
#define NKT   (NNODE/32)   // 192 k-tiles
#define LALPHA 0.2f

typedef unsigned short ushort_t;
typedef unsigned long long u64_t;
typedef short bf16x8 __attribute__((ext_vector_type(8)));
typedef float f32x4 __attribute__((ext_vector_type(4)));

__device__ __forceinline__ float lrelu(float x){ return x > 0.f ? x : LALPHA * x; }

__device__ __forceinline__ ushort_t f2b(float x){
    union { float f; unsigned u; } v; v.f = x;
    unsigned r = v.u + 0x7fffu + ((v.u >> 16) & 1u);
    return (ushort_t)(r >> 16);
}
__device__ __forceinline__ float b2f(ushort_t u){
    union { unsigned u; float f; } v; v.u = ((unsigned)u) << 16; return v.f;
}

// Runtime C/D-layout calibration (round-8 validated)
__device__ __forceinline__ void calib_cd(int lm, int* qrow, int* vcol){
    bf16x8 ai, as;
    ushort_t vi = f2b((float)(lm + 1));
    ushort_t vs = f2b(0.03125f);
    #pragma unroll
    for (int e = 0; e < 8; e++){ ((ushort_t*)&ai)[e] = vi; ((ushort_t*)&as)[e] = vs; }
    f32x4 z = {0.f, 0.f, 0.f, 0.f};
    f32x4 d1 = __builtin_amdgcn_mfma_f32_16x16x32_bf16(ai, as, z, 0, 0, 0);
    f32x4 d2 = __builtin_amdgcn_mfma_f32_16x16x32_bf16(as, ai, z, 0, 0, 0);
    #pragma unroll
    for (int r = 0; r < 4; r++){
        qrow[r] = (int)(d1[r] + 0.5f) - 1;
        vcol[r] = (int)(d2[r] + 0.5f) - 1;
    }
}

// ---------------- adj (int32) -> bitmask ----------------
__global__ void k_adjmask(const int* __restrict__ adj, u64_t* __restrict__ mask){
    int lane = threadIdx.x & 63;
    size_t wid = ((size_t)blockIdx.x * blockDim.x + threadIdx.x) >> 6;
    size_t nw = (size_t)NNODE * NNODE / 64;
    size_t stride = ((size_t)gridDim.x * blockDim.x) >> 6;
    for (size_t q = wid; q < nw; q += stride){
        int a = adj[q * 64 + lane];
        u64_t b = __ballot(a > 0);
        if (lane == 0) mask[q] = b;
    }
}

// out1[r]=W[r]·a[0:K]; out2[r]=W[r]·a[K:2K]  (one wave per row)
__global__ void k_fold(const float* __restrict__ W, const float* __restrict__ a,
                       float* __restrict__ out1, float* __restrict__ out2, int K){
    int row  = (blockIdx.x * blockDim.x + threadIdx.x) >> 6;
    int lane = threadIdx.x & 63;
    const float* wr = W + (size_t)row * K;
    float s1 = 0.f, s2 = 0.f;
    for (int c = lane; c < K; c += 64){ float w = wr[c]; s1 += w * a[c]; s2 += w * a[K + c]; }
    #pragma unroll
    for (int m = 32; m; m >>= 1){ s1 += __shfl_xor(s1, m); s2 += __shfl_xor(s2, m); }
    if (lane == 0){ out1[row] = s1; out2[row] = s2; }
}

// ---------------- o1/o2 = A @ {v1,v2}  (one wave per row) ----------------
__global__ void k_rowvec2_f32(const float* __restrict__ A, const float* __restrict__ v1,
                              const float* __restrict__ v2, float* __restrict__ o1,
                              float* __restrict__ o2, int K){
    int row  = (blockIdx.x * blockDim.x + threadIdx.x) >> 6;
    int lane = threadIdx.x & 63;
    const float* r = A + (size_t)row * K;
    float s1 = 0.f, s2 = 0.f;
    for (int c = lane; c < K; c += 64){ float x = r[c]; s1 += x * v1[c]; s2 += x * v2[c]; }
    #pragma unroll
    for (int m = 32; m; m >>= 1){ s1 += __shfl_xor(s1, m); s2 += __shfl_xor(s2, m); }
    if (lane == 0){ o1[row] = s1; o2[row] = s2; }
}

// ---------------- dst[c*R + r] = bf16(src[r*C + c]) ----------------
__global__ void k_transpose_bf16(const float* __restrict__ src, ushort_t* __restrict__ dst,
                                 int R, int C){
    int idx = blockIdx.x * blockDim.x + threadIdx.x;
    if (idx >= R * C) return;
    int r = idx / C, c = idx - r * C;
    dst[(size_t)c * R + r] = f2b(src[idx]);
}

// ---------------- *out = max(x[0..n)) ----------------
__global__ void k_max(const float* __restrict__ x, int n, float* __restrict__ out){
    __shared__ float sm[16];
    float m = -3.0e38f;
    for (int i = threadIdx.x; i < n; i += blockDim.x) m = fmaxf(m, x[i]);
    #pragma unroll
    for (int s = 32; s; s >>= 1) m = fmaxf(m, __shfl_xor(m, s));
    if ((threadIdx.x & 63) == 0) sm[threadIdx.x >> 6] = m;
    __syncthreads();
    if (threadIdx.x == 0){
        float mm = sm[0];
        for (int i = 1; i < (int)(blockDim.x >> 6); i++) mm = fmaxf(mm, sm[i]);
        *out = mm;
    }
}

// ---------------- Wh1^T via MFMA: writes WhT (fallback layout) + VF (fragment layout) ----------------
// VF[(ci*NKT + ki)*512 + l*8 + e] = Wh1[ki*32 + (l>>4)*8 + e][ci*16 + (l&15)]
__global__ __launch_bounds__(512) void k_gemm_xw(const float* __restrict__ X,
        const ushort_t* __restrict__ B, ushort_t* __restrict__ WhT, ushort_t* __restrict__ VF){
    int i0 = blockIdx.x * 16;
    int w = threadIdx.x >> 6, l = threadIdx.x & 63, lm = l & 15, lh = l >> 4;
    int c0 = w * 64;
    int qrow[4], vcol[4];
    calib_cd(lm, qrow, vcol);
    f32x4 acc[4] = {};
    const float* xp = X + (size_t)(i0 + lm) * FEATD + lh * 8;
    for (int k0 = 0; k0 < FEATD; k0 += 32){
        float4 x0 = *(const float4*)(xp + k0);
        float4 x1 = *(const float4*)(xp + k0 + 4);
        float xa[8] = {x0.x, x0.y, x0.z, x0.w, x1.x, x1.y, x1.z, x1.w};
        bf16x8 af;
        #pragma unroll
        for (int e = 0; e < 8; e++) ((ushort_t*)&af)[e] = f2b(xa[e]);
        #pragma unroll
        for (int t = 0; t < 4; t++){
            bf16x8 bf = *(const bf16x8*)(B + (size_t)(c0 + t*16 + lm) * FEATD + k0 + lh * 8);
            acc[t] = __builtin_amdgcn_mfma_f32_16x16x32_bf16(af, bf, acc[t], 0, 0, 0);
        }
    }
    #pragma unroll
    for (int t = 0; t < 4; t++){
        int ci = (c0 >> 4) + t;
        #pragma unroll
        for (int r = 0; r < 4; r++){
            int node = i0 + qrow[r];
            int col  = c0 + t*16 + vcol[r];
            ushort_t v = f2b(acc[t][r]);
            WhT[(size_t)col * NNODE + node] = v;
            size_t vo = ((size_t)ci * NKT + (node >> 5)) * 512
                      + (size_t)(vcol[r] + ((node >> 3) & 3) * 16) * 8 + (node & 7);
            VF[vo] = v;
        }
    }
}

// ---------------- Wh2 = res @ Wo via MFMA; emits fp32 Wh2 + fragment VF2 ----------------
// VF2[(ci*NKT + ki)*512 + l*8 + e] = Wh2[ki*32 + (l>>4)*8 + e][ci*16 + (l&15)]
__global__ __launch_bounds__(256) void k_gemm_out(const float* __restrict__ res,
        const ushort_t* __restrict__ BT, float* __restrict__ Wh2, ushort_t* __restrict__ VF2){
    int w = threadIdx.x >> 6, l = threadIdx.x & 63, lm = l & 15, lh = l >> 4;
    int i0 = blockIdx.x * 64 + w * 16;
    int qrow[4], vcol[4];
    calib_cd(lm, qrow, vcol);
    f32x4 acc[4] = {};
    const float* ap = res + (size_t)(i0 + lm) * HIDD + lh * 8;
    for (int k0 = 0; k0 < HIDD; k0 += 32){
        float4 x0 = *(const float4*)(ap + k0);
        float4 x1 = *(const float4*)(ap + k0 + 4);
        float xa[8] = {x0.x, x0.y, x0.z, x0.w, x1.x, x1.y, x1.z, x1.w};
        bf16x8 af;
        #pragma unroll
        for (int e = 0; e < 8; e++) ((ushort_t*)&af)[e] = f2b(xa[e]);
        #pragma unroll
        for (int t = 0; t < 4; t++){
            bf16x8 bf = *(const bf16x8*)(BT + (size_t)(t*16 + lm) * HIDD + k0 + lh * 8);
            acc[t] = __builtin_amdgcn_mfma_f32_16x16x32_bf16(af, bf, acc[t], 0, 0, 0);
        }
    }
    #pragma unroll
    for (int t = 0; t < 4; t++){
        #pragma unroll
        for (int r = 0; r < 4; r++){
            int node = i0 + qrow[r], col = t*16 + vcol[r];
            float v = acc[t][r];
            Wh2[(size_t)node * NCLSD + col] = v;
            size_t vo = ((size_t)t * NKT + (node >> 5)) * 512
                      + (size_t)(vcol[r] + ((node >> 3) & 3) * 16) * 8 + (node & 7);
            VF2[vo] = f2b(v);
        }
    }
}

// ---------------- P-gen: fragment layout PF + exact fp32 row sums ----------------
// PF[(ri*NKT + ki)*512 + l*8 + e] = P[ri*16 + (l&15)][ki*32 + (l>>4)*8 + e]
__global__ __launch_bounds__(256) void k_pgen(const u64_t* __restrict__ mask,
        const float* __restrict__ e1, const float* __restrict__ e2,
        const float* __restrict__ e2max, ushort_t* __restrict__ PF, float* __restrict__ lsum){
    __shared__ float e2s[NNODE];
    __shared__ u64_t msk[16][NMSK + 1];
    int ri = blockIdx.x;
    int i0 = ri * 16;
    int tid = threadIdx.x;
    int r = tid >> 4, q = tid & 15;
    for (int k = tid; k < NNODE; k += 256) e2s[k] = e2[k];
    for (int k = tid; k < 16 * NMSK; k += 256) msk[k / NMSK][k % NMSK] = mask[(size_t)i0 * NMSK + k];
    __syncthreads();
    float e1i = e1[i0 + r];
    float M = lrelu(e1i + *e2max);   // exact upper bound (softmax shift-invariant)
    float rsum = 0.f;
    ushort_t* pfb = PF + (size_t)ri * NKT * 512;
    for (int j0 = 0; j0 < NNODE; j0 += 128){
        int j = j0 + q * 8;
        u64_t word = msk[r][j >> 6];
        int sh = j & 63;
        float4 fA = *(const float4*)&e2s[j];
        float4 fB = *(const float4*)&e2s[j + 4];
        float ea[8] = {fA.x, fA.y, fA.z, fA.w, fB.x, fB.y, fB.z, fB.w};
        bf16x8 pk;
        #pragma unroll
        for (int e = 0; e < 8; e++){
            float p = ((word >> (sh + e)) & 1ull) ? __expf(lrelu(e1i + ea[e]) - M) : 0.f;
            ushort_t pb = f2b(p);
            ((ushort_t*)&pk)[e] = pb;
            rsum += b2f(pb);
        }
        int ki = j >> 5;
        int lh = (j >> 3) & 3;
        *(bf16x8*)(pfb + ((size_t)ki * 512 + (size_t)(r + (lh << 4)) * 8)) = pk;
    }
    #pragma unroll
    for (int o = 8; o; o >>= 1) rsum += __shfl_xor(rsum, o);
    if (q == 0) lsum[i0 + r] = rsum;
}

// ---------------- GAT1 GEMM v3: fragment-native loads, fully coalesced ----------------
// grid 768: 16 rows x 256 cols per block; 4 waves of 16x64.
__global__ __launch_bounds__(256) void k_gat1g(const ushort_t* __restrict__ PF,
        const float* __restrict__ lsum, const ushort_t* __restrict__ VF,
        float* __restrict__ res){
    int bid = blockIdx.x;
    int b8 = bid & 7, a = bid >> 3;
    int ch = b8 >> 2;
    int rg = a * 4 + (b8 & 3);
    int i0 = rg * 16;
    int tid = threadIdx.x;
    int w = tid >> 6, l = tid & 63, lm = l & 15, lh = l >> 4;
    int cbase = ch * 256 + w * 64;
    int qrow[4], vcol[4];
    calib_cd(lm, qrow, vcol);
    f32x4 acc[4] = {};
    const ushort_t* Ap = PF + (size_t)rg * NKT * 512 + l * 8;
    const ushort_t* Vp[4];
    #pragma unroll
    for (int t = 0; t < 4; t++)
        Vp[t] = VF + (size_t)((cbase >> 4) + t) * NKT * 512 + l * 8;
    bf16x8 a0c = *(const bf16x8*)(Ap);
    bf16x8 a1c = *(const bf16x8*)(Ap + 512);
    bf16x8 vc[4][2], vn[4][2], a0n = {}, a1n = {};
    #pragma unroll
    for (int t = 0; t < 4; t++){
        vc[t][0] = *(const bf16x8*)(Vp[t]);
        vc[t][1] = *(const bf16x8*)(Vp[t] + 512);
    }
    for (int s = 0; s < NKT/2; s++){
        size_t nb = (size_t)(s + 1) * 1024;
        if (s + 1 < NKT/2){
            a0n = *(const bf16x8*)(Ap + nb);
            a1n = *(const bf16x8*)(Ap + nb + 512);
            #pragma unroll
            for (int t = 0; t < 4; t++){
                vn[t][0] = *(const bf16x8*)(Vp[t] + nb);
                vn[t][1] = *(const bf16x8*)(Vp[t] + nb + 512);
            }
        }
        #pragma unroll
        for (int t = 0; t < 4; t++){
            acc[t] = __builtin_amdgcn_mfma_f32_16x16x32_bf16(a0c, vc[t][0], acc[t], 0, 0, 0);
            acc[t] = __builtin_amdgcn_mfma_f32_16x16x32_bf16(a1c, vc[t][1], acc[t], 0, 0, 0);
        }
        a0c = a0n; a1c = a1n;
        #pragma unroll
        for (int t = 0; t < 4; t++){ vc[t][0] = vn[t][0]; vc[t][1] = vn[t][1]; }
    }
    float den[4];
    #pragma unroll
    for (int r = 0; r < 4; r++) den[r] = lsum[i0 + qrow[r]];
    #pragma unroll
    for (int t = 0; t < 4; t++){
        #pragma unroll
        for (int r = 0; r < 4; r++){
            int row = qrow[r];
            int col = cbase + t*16 + vcol[r];
            float v = acc[t][r] / den[r];
            v = v > 0.f ? v : expm1f(v);   // elu
            res[(size_t)(i0 + row) * HIDD + col] = v;
        }
    }
}

// ---------------- GAT layer 1 fallback (register P, WhT layout) ----------------
__global__ __launch_bounds__(256) void k_gat1(const u64_t* __restrict__ mask,
        const float* __restrict__ e1, const float* __restrict__ e2,
        const float* __restrict__ e2max,
        const ushort_t* __restrict__ V, float* __restrict__ res){
    __shared__ __align__(16) float e2s[NNODE];
    __shared__ u64_t msk[16][NMSK + 1];
    int bid = blockIdx.x;
    int b8 = bid & 7, a = bid >> 3;
    int ch = b8 >> 2;
    int rg = a * 4 + (b8 & 3);
    int i0 = rg * 16;
    int tid = threadIdx.x;
    int w = tid >> 6, l = tid & 63, lm = l & 15, lh = l >> 4;
    int cbase = ch * 256 + w * 64;
    int qrow[4], vcol[4];
    calib_cd(lm, qrow, vcol);
    for (int k = tid; k < NNODE; k += 256) e2s[k] = e2[k];
    for (int k = tid; k < 16 * NMSK; k += 256) msk[k / NMSK][k % NMSK] = mask[(size_t)i0 * NMSK + k];
    __syncthreads();
    float e1i = e1[i0 + lm];
    float M = lrelu(e1i + *e2max);
    float lsum = 0.f;
    f32x4 acc[4] = {};
    const ushort_t* vb[4];
    #pragma unroll
    for (int t = 0; t < 4; t++) vb[t] = V + (size_t)(cbase + t*16 + lm) * NNODE + lh * 8;
    bf16x8 vc[4][2], vn[4][2];
    #pragma unroll
    for (int t = 0; t < 4; t++)
        #pragma unroll
        for (int h = 0; h < 2; h++) vc[t][h] = *(const bf16x8*)(vb[t] + h*32);
    for (int j0 = 0; j0 < NNODE; j0 += 64){
        u64_t word = msk[lm][j0 >> 6];
        int jn = j0 + 64;
        if (jn < NNODE){
            #pragma unroll
            for (int t = 0; t < 4; t++)
                #pragma unroll
                for (int h = 0; h < 2; h++) vn[t][h] = *(const bf16x8*)(vb[t] + jn + h*32);
        }
        #pragma unroll
        for (int h = 0; h < 2; h++){
            int jb = j0 + h*32 + lh*8;
            float4 fA = *(const float4*)&e2s[jb];
            float4 fB = *(const float4*)&e2s[jb + 4];
            float ea[8] = {fA.x, fA.y, fA.z, fA.w, fB.x, fB.y, fB.z, fB.w};
            int sh = h*32 + lh*8;
            bf16x8 pk;
            float ls = 0.f;
            #pragma unroll
            for (int e = 0; e < 8; e++){
                float p = ((word >> (sh + e)) & 1ull) ? __expf(lrelu(e1i + ea[e]) - M) : 0.f;
                ushort_t pb = f2b(p);
                ((ushort_t*)&pk)[e] = pb;
                ls += b2f(pb);
            }
            lsum += ls;
            #pragma unroll
            for (int t = 0; t < 4; t++)
                acc[t] = __builtin_amdgcn_mfma_f32_16x16x32_bf16(pk, vc[t][h], acc[t], 0, 0, 0);
        }
        #pragma unroll
        for (int t = 0; t < 4; t++)
            #pragma unroll
            for (int h = 0; h < 2; h++) vc[t][h] = vn[t][h];
    }
    lsum += __shfl_xor(lsum, 16);
    lsum += __shfl_xor(lsum, 32);
    #pragma unroll
    for (int t = 0; t < 4; t++){
        #pragma unroll
        for (int r = 0; r < 4; r++){
            float den = __shfl(lsum, qrow[r]);
            int row = qrow[r];
            int col = cbase + t*16 + vcol[r];
            float v = acc[t][r] / den;
            v = v > 0.f ? v : expm1f(v);
            res[(size_t)(i0 + row) * HIDD + col] = v;
        }
    }
}

// ---------------- GAT layer 2: 8-wave j-split, fragment-native V2 ----------------
#define JSPAN (NNODE/8)
__global__ __launch_bounds__(512) void k_gat2(const u64_t* __restrict__ mask,
        const float* __restrict__ o1, const float* __restrict__ o2,
        const float* __restrict__ t1, const float* __restrict__ t2,
        const float* __restrict__ o2max, const float* __restrict__ t2max,
        const ushort_t* __restrict__ VF2, float* __restrict__ out2){
    __shared__ float accs[8][16][64];
    __shared__ float lsums[8][16];
    __shared__ u64_t msk[16][NMSK + 1];
    int i0 = blockIdx.x * 16;
    int tid = threadIdx.x;
    int w = tid >> 6, l = tid & 63, lm = l & 15, lh = l >> 4;
    for (int k = tid; k < 16 * NMSK; k += 512) msk[k / NMSK][k % NMSK] = mask[(size_t)i0 * NMSK + k];
    __syncthreads();
    int qrow[4], vcol[4];
    calib_cd(lm, qrow, vcol);
    int jbase = w * JSPAN;
    float o1v = o1[i0 + lm], t1v = t1[i0 + lm];
    float M = lrelu(o1v + *o2max) + lrelu(t1v + *t2max);
    float lsum = 0.f;
    f32x4 acc[4] = {};
    const float* o2p = o2 + jbase + lh * 8;
    const float* t2p = t2 + jbase + lh * 8;
    float4 oA = *(const float4*)(o2p), oB = *(const float4*)(o2p + 4);
    float4 tA = *(const float4*)(t2p), tB = *(const float4*)(t2p + 4);
    const ushort_t* Vp[4];
    #pragma unroll
    for (int t = 0; t < 4; t++)
        Vp[t] = VF2 + (size_t)t * NKT * 512 + (size_t)(jbase >> 5) * 512 + l * 8;
    bf16x8 vcur[4], vnxt[4];
    #pragma unroll
    for (int t = 0; t < 4; t++) vcur[t] = *(const bf16x8*)(Vp[t]);

    for (int js = 0; js < JSPAN; js += 32){
        u64_t w64 = msk[lm][(jbase + js) >> 6];
        int sh = (js + lh * 8) & 63;
        float oa[8] = {oA.x, oA.y, oA.z, oA.w, oB.x, oB.y, oB.z, oB.w};
        float ta[8] = {tA.x, tA.y, tA.z, tA.w, tB.x, tB.y, tB.z, tB.w};
        bf16x8 pk;
        float ls = 0.f;
        #pragma unroll
        for (int e = 0; e < 8; e++){
            float p = ((w64 >> (sh + e)) & 1ull) ?
                      __expf(lrelu(o1v + oa[e]) + lrelu(t1v + ta[e]) - M) : 0.f;
            ushort_t pb = f2b(p);
            ((ushort_t*)&pk)[e] = pb;
            ls += b2f(pb);
        }
        lsum += ls;
        int jn = js + 32;
        if (jn < JSPAN){
            oA = *(const float4*)(o2p + jn); oB = *(const float4*)(o2p + jn + 4);
            tA = *(const float4*)(t2p + jn); tB = *(const float4*)(t2p + jn + 4);
            #pragma unroll
            for (int t = 0; t < 4; t++)
                vnxt[t] = *(const bf16x8*)(Vp[t] + (size_t)(jn >> 5) * 512);
        }
        #pragma unroll
        for (int t = 0; t < 4; t++)
            acc[t] = __builtin_amdgcn_mfma_f32_16x16x32_bf16(pk, vcur[t], acc[t], 0, 0, 0);
        #pragma unroll
        for (int t = 0; t < 4; t++) vcur[t] = vnxt[t];
    }
    lsum += __shfl_xor(lsum, 16);
    lsum += __shfl_xor(lsum, 32);
    if (lh == 0) lsums[w][lm] = lsum;
    #pragma unroll
    for (int t = 0; t < 4; t++)
        #pragma unroll
        for (int r = 0; r < 4; r++)
            accs[w][qrow[r]][t*16 + vcol[r]] = acc[t][r];
    __syncthreads();
    #pragma unroll
    for (int rr = 0; rr < 2; rr++){
        int row = w * 2 + rr;
        float den = 0.f, v = 0.f;
        #pragma unroll
        for (int q = 0; q < 8; q++){ den += lsums[q][row]; v += accs[q][row][l]; }
        out2[(size_t)(i0 + row) * NCLSD + l] = v / den;
    }
}

// ---------------- row-wise log_softmax over 64 classes ----------------
__global__ void k_logsoftmax(const float* __restrict__ out2, float* __restrict__ out){
    int w = threadIdx.x >> 6, l = threadIdx.x & 63;
    int row = blockIdx.x * 4 + w;
    float v = out2[(size_t)row * NCLSD + l];
    float mx = v;
    #pragma unroll
    for (int o = 32; o; o >>= 1) mx = fmaxf(mx, __shfl_xor(mx, o));
    float ex = __expf(v - mx);
    #pragma unroll
    for (int o = 32; o; o >>= 1) ex += __shfl_xor(ex, o);
    out[(size_t)row * NCLSD + l] = v - mx - logf(ex);
}

// ---------------- launch ----------------
extern "C" void kernel_launch(void* const* d_in, const int* in_sizes, int n_in,
                              void* d_out, int out_size, void* d_ws, size_t ws_size,
                              hipStream_t stream){
    const float* X   = (const float*)d_in[0];
    const int*   adj = (const int*)d_in[1];
    const float* Wg  = (const float*)d_in[2];
    const float* ag  = (const float*)d_in[3];
    const float* Wt  = (const float*)d_in[4];
    const float* at  = (const float*)d_in[5];
    const float* Wo  = (const float*)d_in[6];
    const float* ao  = (const float*)d_in[7];
    float* out = (float*)d_out;

    char* ws = (char*)d_ws;
    size_t off = 0;
    auto take = [&](size_t n){ char* p = ws + off; off = (off + n + 255) & ~(size_t)255; return p; };
    u64_t*    maskb = (u64_t*)take((size_t)NNODE * NMSK * 8);
    ushort_t* WhT   = (ushort_t*)take((size_t)HIDD * NNODE * 2);
    ushort_t* VF    = (ushort_t*)take((size_t)HIDD * NNODE * 2);   // fragment layout Wh1
    float*    res   = (float*)take((size_t)NNODE * HIDD * 4);
    float*    Wh2   = (float*)take((size_t)NNODE * NCLSD * 4);
    ushort_t* VF2   = (ushort_t*)take((size_t)NCLSD * NNODE * 2);  // fragment layout Wh2
    ushort_t* WgT   = (ushort_t*)take((size_t)FEATD * HIDD * 2);
    ushort_t* WoT   = (ushort_t*)take((size_t)HIDD * NCLSD * 2);
    float* e1v  = (float*)take(NNODE * 4);
    float* e2v  = (float*)take(NNODE * 4);
    float* t1v  = (float*)take(NNODE * 4);
    float* t2v  = (float*)take(NNODE * 4);
    float* o1v  = (float*)take(NNODE * 4);
    float* o2v  = (float*)take(NNODE * 4);
    float* wg1  = (float*)take(FEATD * 4);
    float* wg2  = (float*)take(FEATD * 4);
    float* wt1  = (float*)take(HIDD * 4);
    float* wt2  = (float*)take(HIDD * 4);
    float* scal = (float*)take(256);
    float* e2m = scal, * t2m = scal + 1, * o2m = scal + 2;
    float* out2 = Wh2;   // alias: gat2 reads only VF2/vectors

    // P fragment buffer (allocated last; only used if ws is big enough)
    size_t pbytes = (size_t)NNODE * NNODE * 2;
    bool bigws = (off + pbytes + NNODE * 4 + 4096) <= ws_size;
    ushort_t* Pbuf  = bigws ? (ushort_t*)take(pbytes) : nullptr;
    float*    lsumv = bigws ? (float*)take(NNODE * 4) : nullptr;

    // adj -> bitmask (reads adj once)
    k_adjmask<<<dim3(2048), dim3(256), 0, stream>>>(adj, maskb);
    // weight prep
    k_transpose_bf16<<<dim3((FEATD*HIDD + 255)/256), dim3(256), 0, stream>>>(Wg, WgT, FEATD, HIDD);
    k_transpose_bf16<<<dim3((HIDD*NCLSD + 255)/256), dim3(256), 0, stream>>>(Wo, WoT, HIDD, NCLSD);
    k_fold<<<dim3(FEATD/4), dim3(256), 0, stream>>>(Wg, ag, wg1, wg2, HIDD);
    k_fold<<<dim3(HIDD/4),  dim3(256), 0, stream>>>(Wt, at, wt1, wt2, HIDD);
    // layer-1 scores (exact fp32 fold)
    k_rowvec2_f32<<<dim3(NNODE/4), dim3(256), 0, stream>>>(X, wg1, wg2, e1v, e2v, FEATD);
    k_max<<<dim3(1), dim3(1024), 0, stream>>>(e2v, NNODE, e2m);
    // Wh1^T via MFMA (both layouts)
    k_gemm_xw<<<dim3(NNODE/16), dim3(512), 0, stream>>>(X, WgT, WhT, VF);
    // GAT layer 1
    if (bigws){
        k_pgen<<<dim3(NNODE/16), dim3(256), 0, stream>>>(maskb, e1v, e2v, e2m, Pbuf, lsumv);
        k_gat1g<<<dim3(NNODE/16 * 2), dim3(256), 0, stream>>>(Pbuf, lsumv, VF, res);
    } else {
        k_gat1<<<dim3(NNODE/16 * 2), dim3(256), 0, stream>>>(maskb, e1v, e2v, e2m, WhT, res);
    }
    // tree scores via fold
    k_rowvec2_f32<<<dim3(NNODE/4), dim3(256), 0, stream>>>(res, wt1, wt2, t1v, t2v, HIDD);
    k_max<<<dim3(1), dim3(1024), 0, stream>>>(t2v, NNODE, t2m);
    // layer-2 prep (MFMA; emits Wh2 fp32 + fragment VF2)
    k_gemm_out<<<dim3(NNODE/64), dim3(256), 0, stream>>>(res, WoT, Wh2, VF2);
    k_rowvec2_f32<<<dim3(NNODE/4), dim3(256), 0, stream>>>(Wh2, ao, ao + NCLSD, o1v, o2v, NCLSD);
    k_max<<<dim3(1), dim3(1024), 0, stream>>>(o2v, NNODE, o2m);
    // GAT layer 2 + log_softmax
    k_gat2<<<dim3(NNODE/16), dim3(512), 0, stream>>>(maskb, o1v, o2v, t1v, t2v, o2m, t2m, VF2, out2);
    k_logsoftmax<<<dim3(NNODE/4), dim3(256), 0, stream>>>(out2, out);
}

// Round 15
// 307.240 us; speedup vs baseline: 1.8742x; 1.0966x over previous
//
#include <hip/hip_runtime.h>

#define NNODE 6144
#define FEATD 512
#define HIDD  512
#define NCLSD 64
#define NMSK  (NNODE/64)   // 96 mask words per row
#define NKT   (NNODE/32)   // 192 k-tiles (node dim)
#define NKTX  (FEATD/32)   // 16 k-tiles (feature dim)
#define LALPHA 0.2f

typedef unsigned short ushort_t;
typedef unsigned long long u64_t;
typedef short bf16x8 __attribute__((ext_vector_type(8)));
typedef float f32x4 __attribute__((ext_vector_type(4)));

__device__ __forceinline__ float lrelu(float x){ return x > 0.f ? x : LALPHA * x; }

__device__ __forceinline__ ushort_t f2b(float x){
    union { float f; unsigned u; } v; v.f = x;
    unsigned r = v.u + 0x7fffu + ((v.u >> 16) & 1u);
    return (ushort_t)(r >> 16);
}
__device__ __forceinline__ float b2f(ushort_t u){
    union { unsigned u; float f; } v; v.u = ((unsigned)u) << 16; return v.f;
}

// Runtime C/D-layout calibration (round-8 validated)
__device__ __forceinline__ void calib_cd(int lm, int* qrow, int* vcol){
    bf16x8 ai, as;
    ushort_t vi = f2b((float)(lm + 1));
    ushort_t vs = f2b(0.03125f);
    #pragma unroll
    for (int e = 0; e < 8; e++){ ((ushort_t*)&ai)[e] = vi; ((ushort_t*)&as)[e] = vs; }
    f32x4 z = {0.f, 0.f, 0.f, 0.f};
    f32x4 d1 = __builtin_amdgcn_mfma_f32_16x16x32_bf16(ai, as, z, 0, 0, 0);
    f32x4 d2 = __builtin_amdgcn_mfma_f32_16x16x32_bf16(as, ai, z, 0, 0, 0);
    #pragma unroll
    for (int r = 0; r < 4; r++){
        qrow[r] = (int)(d1[r] + 0.5f) - 1;
        vcol[r] = (int)(d2[r] + 0.5f) - 1;
    }
}

// ---------------- adj (int32) -> bitmask ----------------
__global__ void k_adjmask(const int* __restrict__ adj, u64_t* __restrict__ mask){
    int lane = threadIdx.x & 63;
    size_t wid = ((size_t)blockIdx.x * blockDim.x + threadIdx.x) >> 6;
    size_t nw = (size_t)NNODE * NNODE / 64;
    size_t stride = ((size_t)gridDim.x * blockDim.x) >> 6;
    for (size_t q = wid; q < nw; q += stride){
        int a = adj[q * 64 + lane];
        u64_t b = __ballot(a > 0);
        if (lane == 0) mask[q] = b;
    }
}

// out1[r]=W[r]·a[0:K]; out2[r]=W[r]·a[K:2K]  (one wave per row)
__global__ void k_fold(const float* __restrict__ W, const float* __restrict__ a,
                       float* __restrict__ out1, float* __restrict__ out2, int K){
    int row  = (blockIdx.x * blockDim.x + threadIdx.x) >> 6;
    int lane = threadIdx.x & 63;
    const float* wr = W + (size_t)row * K;
    float s1 = 0.f, s2 = 0.f;
    for (int c = lane; c < K; c += 64){ float w = wr[c]; s1 += w * a[c]; s2 += w * a[K + c]; }
    #pragma unroll
    for (int m = 32; m; m >>= 1){ s1 += __shfl_xor(s1, m); s2 += __shfl_xor(s2, m); }
    if (lane == 0){ out1[row] = s1; out2[row] = s2; }
}

// ---------------- o1/o2 = A @ {v1,v2}  (one wave per row) ----------------
__global__ void k_rowvec2_f32(const float* __restrict__ A, const float* __restrict__ v1,
                              const float* __restrict__ v2, float* __restrict__ o1,
                              float* __restrict__ o2, int K){
    int row  = (blockIdx.x * blockDim.x + threadIdx.x) >> 6;
    int lane = threadIdx.x & 63;
    const float* r = A + (size_t)row * K;
    float s1 = 0.f, s2 = 0.f;
    for (int c = lane; c < K; c += 64){ float x = r[c]; s1 += x * v1[c]; s2 += x * v2[c]; }
    #pragma unroll
    for (int m = 32; m; m >>= 1){ s1 += __shfl_xor(s1, m); s2 += __shfl_xor(s2, m); }
    if (lane == 0){ o1[row] = s1; o2[row] = s2; }
}

// ---------------- dst[c*R + r] = bf16(src[r*C + c]) ----------------
__global__ void k_transpose_bf16(const float* __restrict__ src, ushort_t* __restrict__ dst,
                                 int R, int C){
    int idx = blockIdx.x * blockDim.x + threadIdx.x;
    if (idx >= R * C) return;
    int r = idx / C, c = idx - r * C;
    dst[(size_t)c * R + r] = f2b(src[idx]);
}

// ---------------- *out = max(x[0..n)) ----------------
__global__ void k_max(const float* __restrict__ x, int n, float* __restrict__ out){
    __shared__ float sm[16];
    float m = -3.0e38f;
    for (int i = threadIdx.x; i < n; i += blockDim.x) m = fmaxf(m, x[i]);
    #pragma unroll
    for (int s = 32; s; s >>= 1) m = fmaxf(m, __shfl_xor(m, s));
    if ((threadIdx.x & 63) == 0) sm[threadIdx.x >> 6] = m;
    __syncthreads();
    if (threadIdx.x == 0){
        float mm = sm[0];
        for (int i = 1; i < (int)(blockDim.x >> 6); i++) mm = fmaxf(mm, sm[i]);
        *out = mm;
    }
}

// ---------------- X -> XF bf16 fragment layout ----------------
// XF[(ri*NKTX + ki)*512 + (r + lh*16)*8 + e] = bf16(X[ri*16 + r][ki*32 + lh*8 + e])
__global__ __launch_bounds__(256) void k_xfrag(const float* __restrict__ X,
                                               ushort_t* __restrict__ XF){
    int ri = blockIdx.x;
    int tid = threadIdx.x;
    int r = tid >> 4, q = tid & 15;
    const float* xp = X + (size_t)(ri * 16 + r) * FEATD;
    ushort_t* xb = XF + (size_t)ri * NKTX * 512;
    for (int j0 = 0; j0 < FEATD; j0 += 128){
        int j = j0 + q * 8;
        float4 fA = *(const float4*)(xp + j);
        float4 fB = *(const float4*)(xp + j + 4);
        float xa[8] = {fA.x, fA.y, fA.z, fA.w, fB.x, fB.y, fB.z, fB.w};
        bf16x8 pk;
        #pragma unroll
        for (int e = 0; e < 8; e++) ((ushort_t*)&pk)[e] = f2b(xa[e]);
        int ki = j >> 5;
        int lh = (j >> 3) & 3;
        *(bf16x8*)(xb + ((size_t)ki * 512 + (size_t)(r + (lh << 4)) * 8)) = pk;
    }
}

// ---------------- Wg -> WgF fragment layout (B-operand) ----------------
// WgF[(ci*NKTX + ki)*512 + l*8 + e] = bf16(Wg[ki*32 + (l>>4)*8 + e][ci*16 + (l&15)])
__global__ __launch_bounds__(256) void k_wgfrag(const float* __restrict__ Wg,
                                                ushort_t* __restrict__ WgF){
    int gid = blockIdx.x * 256 + threadIdx.x;       // one 8-elem slot per thread
    if (gid >= (HIDD/16) * NKTX * 64) return;
    int l = gid & 63, unit = gid >> 6;
    int ci = unit / NKTX, ki = unit - ci * NKTX;
    int lm = l & 15, lh = l >> 4;
    bf16x8 pk;
    #pragma unroll
    for (int e = 0; e < 8; e++)
        ((ushort_t*)&pk)[e] = f2b(Wg[(size_t)(ki*32 + lh*8 + e) * HIDD + ci*16 + lm]);
    *(bf16x8*)(WgF + (size_t)unit * 512 + (size_t)l * 8) = pk;
}

// ---------------- Wh1 = X @ Wg via MFMA, fully coalesced fragment I/O -> VF ----------------
// grid 384 (ri), 512 thr (8 col-group waves).
__global__ __launch_bounds__(512) void k_gemm_xw(const ushort_t* __restrict__ XF,
        const ushort_t* __restrict__ WgF, ushort_t* __restrict__ VF){
    int ri = blockIdx.x;
    int i0 = ri * 16;
    int w = threadIdx.x >> 6, l = threadIdx.x & 63, lm = l & 15;
    int c0 = w * 64;
    int qrow[4], vcol[4];
    calib_cd(lm, qrow, vcol);
    f32x4 acc[4] = {};
    const ushort_t* Ap = XF + (size_t)ri * NKTX * 512 + l * 8;
    const ushort_t* Bp[4];
    #pragma unroll
    for (int t = 0; t < 4; t++)
        Bp[t] = WgF + (size_t)((c0 >> 4) + t) * NKTX * 512 + l * 8;
    for (int ki = 0; ki < NKTX; ki++){
        bf16x8 af = *(const bf16x8*)(Ap + (size_t)ki * 512);
        #pragma unroll
        for (int t = 0; t < 4; t++){
            bf16x8 bf = *(const bf16x8*)(Bp[t] + (size_t)ki * 512);
            acc[t] = __builtin_amdgcn_mfma_f32_16x16x32_bf16(af, bf, acc[t], 0, 0, 0);
        }
    }
    #pragma unroll
    for (int t = 0; t < 4; t++){
        int ci = (c0 >> 4) + t;
        #pragma unroll
        for (int r = 0; r < 4; r++){
            int node = i0 + qrow[r];
            size_t vo = ((size_t)ci * NKT + (node >> 5)) * 512
                      + (size_t)(vcol[r] + ((node >> 3) & 3) * 16) * 8 + (node & 7);
            VF[vo] = f2b(acc[t][r]);
        }
    }
}

// ---------------- Wh2 = res @ Wo via MFMA; emits fp32 Wh2 + fragment VF2 ----------------
__global__ __launch_bounds__(256) void k_gemm_out(const float* __restrict__ res,
        const ushort_t* __restrict__ BT, float* __restrict__ Wh2, ushort_t* __restrict__ VF2){
    int w = threadIdx.x >> 6, l = threadIdx.x & 63, lm = l & 15, lh = l >> 4;
    int i0 = blockIdx.x * 64 + w * 16;
    int qrow[4], vcol[4];
    calib_cd(lm, qrow, vcol);
    f32x4 acc[4] = {};
    const float* ap = res + (size_t)(i0 + lm) * HIDD + lh * 8;
    for (int k0 = 0; k0 < HIDD; k0 += 32){
        float4 x0 = *(const float4*)(ap + k0);
        float4 x1 = *(const float4*)(ap + k0 + 4);
        float xa[8] = {x0.x, x0.y, x0.z, x0.w, x1.x, x1.y, x1.z, x1.w};
        bf16x8 af;
        #pragma unroll
        for (int e = 0; e < 8; e++) ((ushort_t*)&af)[e] = f2b(xa[e]);
        #pragma unroll
        for (int t = 0; t < 4; t++){
            bf16x8 bf = *(const bf16x8*)(BT + (size_t)(t*16 + lm) * HIDD + k0 + lh * 8);
            acc[t] = __builtin_amdgcn_mfma_f32_16x16x32_bf16(af, bf, acc[t], 0, 0, 0);
        }
    }
    #pragma unroll
    for (int t = 0; t < 4; t++){
        #pragma unroll
        for (int r = 0; r < 4; r++){
            int node = i0 + qrow[r], col = t*16 + vcol[r];
            float v = acc[t][r];
            Wh2[(size_t)node * NCLSD + col] = v;
            size_t vo = ((size_t)t * NKT + (node >> 5)) * 512
                      + (size_t)(vcol[r] + ((node >> 3) & 3) * 16) * 8 + (node & 7);
            VF2[vo] = f2b(v);
        }
    }
}

// ---------------- P-gen: fragment layout PF + exact fp32 row sums ----------------
__global__ __launch_bounds__(256) void k_pgen(const u64_t* __restrict__ mask,
        const float* __restrict__ e1, const float* __restrict__ e2,
        const float* __restrict__ e2max, ushort_t* __restrict__ PF, float* __restrict__ lsum){
    __shared__ float e2s[NNODE];
    __shared__ u64_t msk[16][NMSK + 1];
    int ri = blockIdx.x;
    int i0 = ri * 16;
    int tid = threadIdx.x;
    int r = tid >> 4, q = tid & 15;
    for (int k = tid; k < NNODE; k += 256) e2s[k] = e2[k];
    for (int k = tid; k < 16 * NMSK; k += 256) msk[k / NMSK][k % NMSK] = mask[(size_t)i0 * NMSK + k];
    __syncthreads();
    float e1i = e1[i0 + r];
    float M = lrelu(e1i + *e2max);   // exact upper bound (softmax shift-invariant)
    float rsum = 0.f;
    ushort_t* pfb = PF + (size_t)ri * NKT * 512;
    for (int j0 = 0; j0 < NNODE; j0 += 128){
        int j = j0 + q * 8;
        u64_t word = msk[r][j >> 6];
        int sh = j & 63;
        float4 fA = *(const float4*)&e2s[j];
        float4 fB = *(const float4*)&e2s[j + 4];
        float ea[8] = {fA.x, fA.y, fA.z, fA.w, fB.x, fB.y, fB.z, fB.w};
        bf16x8 pk;
        #pragma unroll
        for (int e = 0; e < 8; e++){
            float p = ((word >> (sh + e)) & 1ull) ? __expf(lrelu(e1i + ea[e]) - M) : 0.f;
            ushort_t pb = f2b(p);
            ((ushort_t*)&pk)[e] = pb;
            rsum += b2f(pb);
        }
        int ki = j >> 5;
        int lh = (j >> 3) & 3;
        *(bf16x8*)(pfb + ((size_t)ki * 512 + (size_t)(r + (lh << 4)) * 8)) = pk;
    }
    #pragma unroll
    for (int o = 8; o; o >>= 1) rsum += __shfl_xor(rsum, o);
    if (q == 0) lsum[i0 + r] = rsum;
}

// ---------------- GAT1 GEMM v4: 64-row x 64-col blocks, stacked waves ----------------
// grid 768: c8 = bid&7 (col-group <-> XCD), rg = bid>>3 (64-row group).
// 4 waves stacked on rows share one 64-col V slice (L1-captured).
__global__ __launch_bounds__(256) void k_gat1g(const ushort_t* __restrict__ PF,
        const float* __restrict__ lsum, const ushort_t* __restrict__ VF,
        float* __restrict__ res){
    int bid = blockIdx.x;
    int c8 = bid & 7, rg = bid >> 3;
    int tid = threadIdx.x;
    int w = tid >> 6, l = tid & 63, lm = l & 15;
    int ri = rg * 4 + w;           // this wave's 16-row group
    int i0 = ri * 16;
    int cbase = c8 * 64;
    int qrow[4], vcol[4];
    calib_cd(lm, qrow, vcol);
    f32x4 acc[4] = {};
    const ushort_t* Ap = PF + (size_t)ri * NKT * 512 + l * 8;
    const ushort_t* Vp[4];
    #pragma unroll
    for (int t = 0; t < 4; t++)
        Vp[t] = VF + (size_t)(c8 * 4 + t) * NKT * 512 + l * 8;
    bf16x8 a0c = *(const bf16x8*)(Ap);
    bf16x8 a1c = *(const bf16x8*)(Ap + 512);
    bf16x8 vc[4][2], vn[4][2], a0n = {}, a1n = {};
    #pragma unroll
    for (int t = 0; t < 4; t++){
        vc[t][0] = *(const bf16x8*)(Vp[t]);
        vc[t][1] = *(const bf16x8*)(Vp[t] + 512);
    }
    for (int s = 0; s < NKT/2; s++){
        size_t nb = (size_t)(s + 1) * 1024;
        if (s + 1 < NKT/2){
            a0n = *(const bf16x8*)(Ap + nb);
            a1n = *(const bf16x8*)(Ap + nb + 512);
            #pragma unroll
            for (int t = 0; t < 4; t++){
                vn[t][0] = *(const bf16x8*)(Vp[t] + nb);
                vn[t][1] = *(const bf16x8*)(Vp[t] + nb + 512);
            }
        }
        #pragma unroll
        for (int t = 0; t < 4; t++){
            acc[t] = __builtin_amdgcn_mfma_f32_16x16x32_bf16(a0c, vc[t][0], acc[t], 0, 0, 0);
            acc[t] = __builtin_amdgcn_mfma_f32_16x16x32_bf16(a1c, vc[t][1], acc[t], 0, 0, 0);
        }
        a0c = a0n; a1c = a1n;
        #pragma unroll
        for (int t = 0; t < 4; t++){ vc[t][0] = vn[t][0]; vc[t][1] = vn[t][1]; }
    }
    float den[4];
    #pragma unroll
    for (int r = 0; r < 4; r++) den[r] = lsum[i0 + qrow[r]];
    #pragma unroll
    for (int t = 0; t < 4; t++){
        #pragma unroll
        for (int r = 0; r < 4; r++){
            int row = qrow[r];
            int col = cbase + t*16 + vcol[r];
            float v = acc[t][r] / den[r];
            v = v > 0.f ? v : expm1f(v);   // elu
            res[(size_t)(i0 + row) * HIDD + col] = v;
        }
    }
}

// ---------------- GAT layer 1 fallback (register P, VF layout) ----------------
__global__ __launch_bounds__(256) void k_gat1(const u64_t* __restrict__ mask,
        const float* __restrict__ e1, const float* __restrict__ e2,
        const float* __restrict__ e2max,
        const ushort_t* __restrict__ VF, float* __restrict__ res){
    __shared__ __align__(16) float e2s[NNODE];
    __shared__ u64_t msk[16][NMSK + 1];
    int bid = blockIdx.x;
    int b8 = bid & 7, a = bid >> 3;
    int ch = b8 >> 2;
    int rg = a * 4 + (b8 & 3);
    int i0 = rg * 16;
    int tid = threadIdx.x;
    int w = tid >> 6, l = tid & 63, lm = l & 15, lh = l >> 4;
    int cbase = ch * 256 + w * 64;
    int qrow[4], vcol[4];
    calib_cd(lm, qrow, vcol);
    for (int k = tid; k < NNODE; k += 256) e2s[k] = e2[k];
    for (int k = tid; k < 16 * NMSK; k += 256) msk[k / NMSK][k % NMSK] = mask[(size_t)i0 * NMSK + k];
    __syncthreads();
    float e1i = e1[i0 + lm];
    float M = lrelu(e1i + *e2max);
    float lsum = 0.f;
    f32x4 acc[4] = {};
    const ushort_t* Vp[4];
    #pragma unroll
    for (int t = 0; t < 4; t++)
        Vp[t] = VF + (size_t)((cbase >> 4) + t) * NKT * 512 + l * 8;
    bf16x8 vc[4][2], vn[4][2];
    #pragma unroll
    for (int t = 0; t < 4; t++)
        #pragma unroll
        for (int h = 0; h < 2; h++) vc[t][h] = *(const bf16x8*)(Vp[t] + h * 512);
    for (int j0 = 0; j0 < NNODE; j0 += 64){
        u64_t word = msk[lm][j0 >> 6];
        int jn = j0 + 64;
        if (jn < NNODE){
            size_t nb = (size_t)(jn >> 5) * 512;
            #pragma unroll
            for (int t = 0; t < 4; t++)
                #pragma unroll
                for (int h = 0; h < 2; h++) vn[t][h] = *(const bf16x8*)(Vp[t] + nb + h * 512);
        }
        #pragma unroll
        for (int h = 0; h < 2; h++){
            int jb = j0 + h*32 + lh*8;
            float4 fA = *(const float4*)&e2s[jb];
            float4 fB = *(const float4*)&e2s[jb + 4];
            float ea[8] = {fA.x, fA.y, fA.z, fA.w, fB.x, fB.y, fB.z, fB.w};
            int sh = h*32 + lh*8;
            bf16x8 pk;
            float ls = 0.f;
            #pragma unroll
            for (int e = 0; e < 8; e++){
                float p = ((word >> (sh + e)) & 1ull) ? __expf(lrelu(e1i + ea[e]) - M) : 0.f;
                ushort_t pb = f2b(p);
                ((ushort_t*)&pk)[e] = pb;
                ls += b2f(pb);
            }
            lsum += ls;
            #pragma unroll
            for (int t = 0; t < 4; t++)
                acc[t] = __builtin_amdgcn_mfma_f32_16x16x32_bf16(pk, vc[t][h], acc[t], 0, 0, 0);
        }
        #pragma unroll
        for (int t = 0; t < 4; t++)
            #pragma unroll
            for (int h = 0; h < 2; h++) vc[t][h] = vn[t][h];
    }
    lsum += __shfl_xor(lsum, 16);
    lsum += __shfl_xor(lsum, 32);
    #pragma unroll
    for (int t = 0; t < 4; t++){
        #pragma unroll
        for (int r = 0; r < 4; r++){
            float den = __shfl(lsum, qrow[r]);
            int row = qrow[r];
            int col = cbase + t*16 + vcol[r];
            float v = acc[t][r] / den;
            v = v > 0.f ? v : expm1f(v);
            res[(size_t)(i0 + row) * HIDD + col] = v;
        }
    }
}

// ---------------- GAT layer 2: 8-wave j-split, fragment-native V2 ----------------
#define JSPAN (NNODE/8)
__global__ __launch_bounds__(512) void k_gat2(const u64_t* __restrict__ mask,
        const float* __restrict__ o1, const float* __restrict__ o2,
        const float* __restrict__ t1, const float* __restrict__ t2,
        const float* __restrict__ o2max, const float* __restrict__ t2max,
        const ushort_t* __restrict__ VF2, float* __restrict__ out2){
    __shared__ float accs[8][16][64];
    __shared__ float lsums[8][16];
    __shared__ u64_t msk[16][NMSK + 1];
    int i0 = blockIdx.x * 16;
    int tid = threadIdx.x;
    int w = tid >> 6, l = tid & 63, lm = l & 15, lh = l >> 4;
    for (int k = tid; k < 16 * NMSK; k += 512) msk[k / NMSK][k % NMSK] = mask[(size_t)i0 * NMSK + k];
    __syncthreads();
    int qrow[4], vcol[4];
    calib_cd(lm, qrow, vcol);
    int jbase = w * JSPAN;
    float o1v = o1[i0 + lm], t1v = t1[i0 + lm];
    float M = lrelu(o1v + *o2max) + lrelu(t1v + *t2max);
    float lsum = 0.f;
    f32x4 acc[4] = {};
    const float* o2p = o2 + jbase + lh * 8;
    const float* t2p = t2 + jbase + lh * 8;
    float4 oA = *(const float4*)(o2p), oB = *(const float4*)(o2p + 4);
    float4 tA = *(const float4*)(t2p), tB = *(const float4*)(t2p + 4);
    const ushort_t* Vp[4];
    #pragma unroll
    for (int t = 0; t < 4; t++)
        Vp[t] = VF2 + (size_t)t * NKT * 512 + (size_t)(jbase >> 5) * 512 + l * 8;
    bf16x8 vcur[4], vnxt[4];
    #pragma unroll
    for (int t = 0; t < 4; t++) vcur[t] = *(const bf16x8*)(Vp[t]);

    for (int js = 0; js < JSPAN; js += 32){
        u64_t w64 = msk[lm][(jbase + js) >> 6];
        int sh = (js + lh * 8) & 63;
        float oa[8] = {oA.x, oA.y, oA.z, oA.w, oB.x, oB.y, oB.z, oB.w};
        float ta[8] = {tA.x, tA.y, tA.z, tA.w, tB.x, tB.y, tB.z, tB.w};
        bf16x8 pk;
        float ls = 0.f;
        #pragma unroll
        for (int e = 0; e < 8; e++){
            float p = ((w64 >> (sh + e)) & 1ull) ?
                      __expf(lrelu(o1v + oa[e]) + lrelu(t1v + ta[e]) - M) : 0.f;
            ushort_t pb = f2b(p);
            ((ushort_t*)&pk)[e] = pb;
            ls += b2f(pb);
        }
        lsum += ls;
        int jn = js + 32;
        if (jn < JSPAN){
            oA = *(const float4*)(o2p + jn); oB = *(const float4*)(o2p + jn + 4);
            tA = *(const float4*)(t2p + jn); tB = *(const float4*)(t2p + jn + 4);
            #pragma unroll
            for (int t = 0; t < 4; t++)
                vnxt[t] = *(const bf16x8*)(Vp[t] + (size_t)(jn >> 5) * 512);
        }
        #pragma unroll
        for (int t = 0; t < 4; t++)
            acc[t] = __builtin_amdgcn_mfma_f32_16x16x32_bf16(pk, vcur[t], acc[t], 0, 0, 0);
        #pragma unroll
        for (int t = 0; t < 4; t++) vcur[t] = vnxt[t];
    }
    lsum += __shfl_xor(lsum, 16);
    lsum += __shfl_xor(lsum, 32);
    if (lh == 0) lsums[w][lm] = lsum;
    #pragma unroll
    for (int t = 0; t < 4; t++)
        #pragma unroll
        for (int r = 0; r < 4; r++)
            accs[w][qrow[r]][t*16 + vcol[r]] = acc[t][r];
    __syncthreads();
    #pragma unroll
    for (int rr = 0; rr < 2; rr++){
        int row = w * 2 + rr;
        float den = 0.f, v = 0.f;
        #pragma unroll
        for (int q = 0; q < 8; q++){ den += lsums[q][row]; v += accs[q][row][l]; }
        out2[(size_t)(i0 + row) * NCLSD + l] = v / den;
    }
}

// ---------------- row-wise log_softmax over 64 classes ----------------
__global__ void k_logsoftmax(const float* __restrict__ out2, float* __restrict__ out){
    int w = threadIdx.x >> 6, l = threadIdx.x & 63;
    int row = blockIdx.x * 4 + w;
    float v = out2[(size_t)row * NCLSD + l];
    float mx = v;
    #pragma unroll
    for (int o = 32; o; o >>= 1) mx = fmaxf(mx, __shfl_xor(mx, o));
    float ex = __expf(v - mx);
    #pragma unroll
    for (int o = 32; o; o >>= 1) ex += __shfl_xor(ex, o);
    out[(size_t)row * NCLSD + l] = v - mx - logf(ex);
}

// ---------------- launch ----------------
extern "C" void kernel_launch(void* const* d_in, const int* in_sizes, int n_in,
                              void* d_out, int out_size, void* d_ws, size_t ws_size,
                              hipStream_t stream){
    const float* X   = (const float*)d_in[0];
    const int*   adj = (const int*)d_in[1];
    const float* Wg  = (const float*)d_in[2];
    const float* ag  = (const float*)d_in[3];
    const float* Wt  = (const float*)d_in[4];
    const float* at  = (const float*)d_in[5];
    const float* Wo  = (const float*)d_in[6];
    const float* ao  = (const float*)d_in[7];
    float* out = (float*)d_out;

    char* ws = (char*)d_ws;
    size_t off = 0;
    auto take = [&](size_t n){ char* p = ws + off; off = (off + n + 255) & ~(size_t)255; return p; };
    u64_t*    maskb = (u64_t*)take((size_t)NNODE * NMSK * 8);
    ushort_t* VF    = (ushort_t*)take((size_t)HIDD * NNODE * 2);   // fragment layout Wh1
    float*    res   = (float*)take((size_t)NNODE * HIDD * 4);
    float*    Wh2   = (float*)take((size_t)NNODE * NCLSD * 4);
    ushort_t* VF2   = (ushort_t*)take((size_t)NCLSD * NNODE * 2);  // fragment layout Wh2
    ushort_t* XF    = (ushort_t*)take((size_t)NNODE * FEATD * 2);  // fragment layout X
    ushort_t* WgF   = (ushort_t*)take((size_t)FEATD * HIDD * 2);   // fragment layout Wg
    ushort_t* WoT   = (ushort_t*)take((size_t)HIDD * NCLSD * 2);
    float* e1v  = (float*)take(NNODE * 4);
    float* e2v  = (float*)take(NNODE * 4);
    float* t1v  = (float*)take(NNODE * 4);
    float* t2v  = (float*)take(NNODE * 4);
    float* o1v  = (float*)take(NNODE * 4);
    float* o2v  = (float*)take(NNODE * 4);
    float* wg1  = (float*)take(FEATD * 4);
    float* wg2  = (float*)take(FEATD * 4);
    float* wt1  = (float*)take(HIDD * 4);
    float* wt2  = (float*)take(HIDD * 4);
    float* scal = (float*)take(256);
    float* e2m = scal, * t2m = scal + 1, * o2m = scal + 2;
    float* out2 = Wh2;   // alias: gat2 reads only VF2/vectors

    // P fragment buffer (allocated last; only used if ws is big enough)
    size_t pbytes = (size_t)NNODE * NNODE * 2;
    bool bigws = (off + pbytes + NNODE * 4 + 4096) <= ws_size;
    ushort_t* Pbuf  = bigws ? (ushort_t*)take(pbytes) : nullptr;
    float*    lsumv = bigws ? (float*)take(NNODE * 4) : nullptr;

    // adj -> bitmask (reads adj once)
    k_adjmask<<<dim3(2048), dim3(256), 0, stream>>>(adj, maskb);
    // weight prep
    k_transpose_bf16<<<dim3((HIDD*NCLSD + 255)/256), dim3(256), 0, stream>>>(Wo, WoT, HIDD, NCLSD);
    k_fold<<<dim3(FEATD/4), dim3(256), 0, stream>>>(Wg, ag, wg1, wg2, HIDD);
    k_fold<<<dim3(HIDD/4),  dim3(256), 0, stream>>>(Wt, at, wt1, wt2, HIDD);
    // layer-1 scores (exact fp32 fold)
    k_rowvec2_f32<<<dim3(NNODE/4), dim3(256), 0, stream>>>(X, wg1, wg2, e1v, e2v, FEATD);
    k_max<<<dim3(1), dim3(1024), 0, stream>>>(e2v, NNODE, e2m);
    // fragmentize inputs + Wh1 via MFMA (coalesced)
    k_xfrag<<<dim3(NNODE/16), dim3(256), 0, stream>>>(X, XF);
    k_wgfrag<<<dim3(((HIDD/16)*NKTX*64 + 255)/256), dim3(256), 0, stream>>>(Wg, WgF);
    k_gemm_xw<<<dim3(NNODE/16), dim3(512), 0, stream>>>(XF, WgF, VF);
    // GAT layer 1
    if (bigws){
        k_pgen<<<dim3(NNODE/16), dim3(256), 0, stream>>>(maskb, e1v, e2v, e2m, Pbuf, lsumv);
        k_gat1g<<<dim3(NNODE/64 * 8), dim3(256), 0, stream>>>(Pbuf, lsumv, VF, res);
    } else {
        k_gat1<<<dim3(NNODE/16 * 2), dim3(256), 0, stream>>>(maskb, e1v, e2v, e2m, VF, res);
    }
    // tree scores via fold
    k_rowvec2_f32<<<dim3(NNODE/4), dim3(256), 0, stream>>>(res, wt1, wt2, t1v, t2v, HIDD);
    k_max<<<dim3(1), dim3(1024), 0, stream>>>(t2v, NNODE, t2m);
    // layer-2 prep (MFMA; emits Wh2 fp32 + fragment VF2)
    k_gemm_out<<<dim3(NNODE/64), dim3(256), 0, stream>>>(res, WoT, Wh2, VF2);
    k_rowvec2_f32<<<dim3(NNODE/4), dim3(256), 0, stream>>>(Wh2, ao, ao + NCLSD, o1v, o2v, NCLSD);
    k_max<<<dim3(1), dim3(1024), 0, stream>>>(o2v, NNODE, o2m);
    // GAT layer 2 + log_softmax
    k_gat2<<<dim3(NNODE/16), dim3(512), 0, stream>>>(maskb, o1v, o2v, t1v, t2v, o2m, t2m, VF2, out2);
    k_logsoftmax<<<dim3(NNODE/4), dim3(256), 0, stream>>>(out2, out);
}